// Round 1
// baseline (3316.090 us; speedup 1.0000x reference)
//
#include <hip/hip_runtime.h>
#include <hip/hip_bf16.h>

// Problem constants (from reference):
// B=2, T=64, V=32000, NH=32, HD=32, C=1024. BT=128, rows M = BT*NH = 4096.
#define NV     32000
#define NHD    32         // head dim == n_head
#define MROWS  4096       // BT * NH
#define VSLICES 8
#define VSL_LEN (NV / VSLICES)   // 4000
#define RPB    4          // rows per fused block

// ws layout (floats):
//   vs   : [NV][32]           at 0          (1,024,000 floats)
//   F    : [MROWS][32]        at 1,024,000  (131,072 floats)
//   part : [MROWS/RPB * VSLICES][RPB*33] at 1,155,072 (8192*132 floats)
#define WS_VS_OFF   0
#define WS_F_OFF    1024000
#define WS_PART_OFF 1155072

// ---------------- Kernel A: vocab channel sums ----------------
// vs[v*32+h] = sum_d emb[v*1024 + h*32 + d]
__global__ void vsum_kernel(const float* __restrict__ emb, float* __restrict__ vs) {
    int t = blockIdx.x * 256 + threadIdx.x;      // t = v*32 + h
    if (t >= NV * NHD) return;
    int v = t >> 5, h = t & 31;
    const float4* p = (const float4*)(emb + (size_t)v * 1024 + h * 32);
    float s = 0.f;
#pragma unroll
    for (int i = 0; i < 8; ++i) {
        float4 a = p[i];
        s += a.x + a.y + a.z + a.w;
    }
    vs[t] = s;
}

// ---------------- Kernel B: per-head FFN ----------------
// F[frow*32+d] = sum_h x[frow*32+h] * W[d*32+h] + b[d]
// (frow = bt*32+n; x flat offset bt*1024+n*32 == frow*32)
__global__ void ffn_kernel(const float* __restrict__ x, const float* __restrict__ W,
                           const float* __restrict__ b, float* __restrict__ F) {
    int t = blockIdx.x * 256 + threadIdx.x;      // t = frow*32 + d
    if (t >= MROWS * NHD) return;
    int frow = t >> 5, d = t & 31;
    const float4* xp = (const float4*)(x + (size_t)frow * 32);
    const float4* wp = (const float4*)(W + (size_t)d * 32);
    float s = b[d];
#pragma unroll
    for (int i = 0; i < 8; ++i) {
        float4 xv = xp[i];
        float4 wv = wp[i];
        s += xv.x * wv.x + xv.y * wv.y + xv.z * wv.z + xv.w * wv.w;
    }
    F[t] = s;
}

// ---------------- Kernel C: fused logits+softmax(nomax)+PV, V-sliced ----------------
// One block: RPB=4 rows x one V-slice of 4000. Partial acc[4][32], l[4] -> ws.
// blockIdx.x = rowgroup*8 + vslice  (vslice = blockIdx%8 -> XCD-local slice reuse)
__global__ __launch_bounds__(256, 2)
void fused_kernel(const float* __restrict__ vs, const float* __restrict__ F,
                  const float* __restrict__ temps, float* __restrict__ part) {
    const int b = blockIdx.x;
    const int vslice = b & 7;
    const int rowgroup = b >> 3;
    const int rowbase = rowgroup * RPB;
    const int tid = threadIdx.x;

    __shared__ float Fs[RPB * 32];
    __shared__ float red[4][RPB * 33];

    if (tid < RPB * 32) Fs[tid] = F[rowbase * 32 + tid];

    float invt[RPB];
#pragma unroll
    for (int r = 0; r < RPB; ++r) {
        int n = (rowbase + r) & 31;
        invt[r] = 1.0f / fmaxf(temps[n], 0.1f);
    }
    __syncthreads();

    float acc[RPB][32];
    float lsum[RPB];
#pragma unroll
    for (int r = 0; r < RPB; ++r) {
        lsum[r] = 0.f;
#pragma unroll
        for (int k = 0; k < 32; ++k) acc[r][k] = 0.f;
    }

    const int V0 = vslice * VSL_LEN;
    for (int v = V0 + tid; v < V0 + VSL_LEN; v += 256) {
        float4 q[8];
        const float4* vp = (const float4*)(vs + (size_t)v * 32);
#pragma unroll
        for (int i = 0; i < 8; ++i) q[i] = vp[i];

        const float4* fp = (const float4*)Fs;
#pragma unroll
        for (int r = 0; r < RPB; ++r) {
            float s = 0.f;
#pragma unroll
            for (int i = 0; i < 8; ++i) {
                float4 f = fp[r * 8 + i];
                s += f.x * q[i].x + f.y * q[i].y + f.z * q[i].z + f.w * q[i].w;
            }
            float w = __expf(s * invt[r]);
            lsum[r] += w;
#pragma unroll
            for (int i = 0; i < 8; ++i) {
                acc[r][i * 4 + 0] += w * q[i].x;
                acc[r][i * 4 + 1] += w * q[i].y;
                acc[r][i * 4 + 2] += w * q[i].z;
                acc[r][i * 4 + 3] += w * q[i].w;
            }
        }
    }

    // Wave butterfly reduction (64 lanes), then cross-wave via LDS.
#pragma unroll
    for (int r = 0; r < RPB; ++r) {
#pragma unroll
        for (int k = 0; k < 32; ++k) {
            float x = acc[r][k];
            for (int off = 1; off < 64; off <<= 1) x += __shfl_xor(x, off, 64);
            acc[r][k] = x;
        }
        float lv = lsum[r];
        for (int off = 1; off < 64; off <<= 1) lv += __shfl_xor(lv, off, 64);
        lsum[r] = lv;
    }

    const int wave = tid >> 6;
    if ((tid & 63) == 0) {
#pragma unroll
        for (int r = 0; r < RPB; ++r) {
#pragma unroll
            for (int k = 0; k < 32; ++k) red[wave][r * 33 + k] = acc[r][k];
            red[wave][r * 33 + 32] = lsum[r];
        }
    }
    __syncthreads();

    if (tid < RPB * 33) {
        float s = red[0][tid] + red[1][tid] + red[2][tid] + red[3][tid];
        part[(size_t)b * (RPB * 33) + tid] = s;
    }
}

// ---------------- Kernel D: combine V-slice partials ----------------
__global__ void combine_kernel(const float* __restrict__ part, float* __restrict__ out) {
    int t = blockIdx.x * 256 + threadIdx.x;      // t = frow*32 + h
    if (t >= MROWS * NHD) return;
    int frow = t >> 5, h = t & 31;
    int rg = frow >> 2, i = frow & 3;
    float a = 0.f, l = 0.f;
#pragma unroll
    for (int s = 0; s < VSLICES; ++s) {
        const float* p = part + (size_t)(rg * VSLICES + s) * (RPB * 33) + i * 33;
        a += p[h];
        l += p[32];
    }
    out[t] = a / l;
}

extern "C" void kernel_launch(void* const* d_in, const int* in_sizes, int n_in,
                              void* d_out, int out_size, void* d_ws, size_t ws_size,
                              hipStream_t stream) {
    const float* x     = (const float*)d_in[0];   // (2,64,1024)
    const float* W     = (const float*)d_in[1];   // (32,32)
    const float* bias  = (const float*)d_in[2];   // (32,)
    const float* temps = (const float*)d_in[3];   // (32,)
    const float* emb   = (const float*)d_in[4];   // (32000,1024)
    float* out = (float*)d_out;                   // (2,64,1024) fp32

    float* ws   = (float*)d_ws;
    float* vs   = ws + WS_VS_OFF;
    float* F    = ws + WS_F_OFF;
    float* part = ws + WS_PART_OFF;

    vsum_kernel<<<(NV * NHD + 255) / 256, 256, 0, stream>>>(emb, vs);
    ffn_kernel<<<(MROWS * NHD + 255) / 256, 256, 0, stream>>>(x, W, bias, F);
    fused_kernel<<<(MROWS / RPB) * VSLICES, 256, 0, stream>>>(vs, F, temps, part);
    combine_kernel<<<(MROWS * NHD + 255) / 256, 256, 0, stream>>>(part, out);
}

// Round 2
// 392.506 us; speedup vs baseline: 8.4485x; 8.4485x over previous
//
#include <hip/hip_runtime.h>
#include <hip/hip_bf16.h>

// Problem constants (from reference):
// B=2, T=64, V=32000, NH=32, HD=32, C=1024. BT=128, rows M = BT*NH = 4096.
#define NV     32000
#define NHD    32         // head dim == n_head
#define MROWS  4096       // BT * NH
#define VSLICES 8
#define VSL_LEN (NV / VSLICES)   // 4000
#define RPB    4          // rows per fused block

// ws layout (floats):
//   vs   : [NV][32]           at 0          (1,024,000 floats)
//   F    : [MROWS][32]        at 1,024,000  (131,072 floats)
//   part : [MROWS/RPB * VSLICES][RPB*33] at 1,155,072 (8192*132 floats)
#define WS_VS_OFF   0
#define WS_F_OFF    1024000
#define WS_PART_OFF 1155072

// ---------------- Kernel A: vocab channel sums ----------------
// vs[v*32+h] = sum_d emb[v*1024 + h*32 + d]
__global__ void vsum_kernel(const float* __restrict__ emb, float* __restrict__ vs) {
    int t = blockIdx.x * 256 + threadIdx.x;      // t = v*32 + h
    if (t >= NV * NHD) return;
    int v = t >> 5, h = t & 31;
    const float4* p = (const float4*)(emb + (size_t)v * 1024 + h * 32);
    float s = 0.f;
#pragma unroll
    for (int i = 0; i < 8; ++i) {
        float4 a = p[i];
        s += a.x + a.y + a.z + a.w;
    }
    vs[t] = s;
}

// ---------------- Kernel B: per-head FFN ----------------
// F[frow*32+d] = sum_h x[frow*32+h] * W[d*32+h] + b[d]
__global__ void ffn_kernel(const float* __restrict__ x, const float* __restrict__ W,
                           const float* __restrict__ b, float* __restrict__ F) {
    int t = blockIdx.x * 256 + threadIdx.x;      // t = frow*32 + d
    if (t >= MROWS * NHD) return;
    int frow = t >> 5, d = t & 31;
    const float4* xp = (const float4*)(x + (size_t)frow * 32);
    const float4* wp = (const float4*)(W + (size_t)d * 32);
    float s = b[d];
#pragma unroll
    for (int i = 0; i < 8; ++i) {
        float4 xv = xp[i];
        float4 wv = wp[i];
        s += xv.x * wv.x + xv.y * wv.y + xv.z * wv.z + xv.w * wv.w;
    }
    F[t] = s;
}

// ---------------- Kernel C: fused logits+softmax(nomax)+PV, V-sliced ----------------
// 256 threads = 4 waves. lane = vl*4 + kg: vl in 0..15 picks the v row,
// kg in 0..3 picks an 8-wide slice of the 32 channel dims.
// Registers per lane: F[4][8]=32, acc[4][8]=32, q=8 -> ~100 VGPR, no spill.
__global__ __launch_bounds__(256, 4)
void fused_kernel(const float* __restrict__ vs, const float* __restrict__ F,
                  const float* __restrict__ temps, float* __restrict__ part) {
    const int b = blockIdx.x;
    const int vslice = b & 7;
    const int rowbase = (b >> 3) * RPB;
    const int tid = threadIdx.x;
    const int wave = tid >> 6;
    const int lane = tid & 63;
    const int vl = lane >> 2;    // 0..15
    const int kg = lane & 3;     // 0..3

    __shared__ float red[4][RPB * 33];

    float4 fa[RPB], fb[RPB];
    float invt[RPB], lsum[RPB];
    float4 aa[RPB], ab[RPB];
#pragma unroll
    for (int r = 0; r < RPB; ++r) {
        const float4* fp = (const float4*)(F + (size_t)(rowbase + r) * 32 + kg * 8);
        fa[r] = fp[0];
        fb[r] = fp[1];
        invt[r] = 1.0f / fmaxf(temps[(rowbase + r) & 31], 0.1f);
        lsum[r] = 0.f;
        aa[r] = make_float4(0.f, 0.f, 0.f, 0.f);
        ab[r] = make_float4(0.f, 0.f, 0.f, 0.f);
    }

    const int V0 = vslice * VSL_LEN;
    for (int voff = wave * 16 + vl; voff < VSL_LEN; voff += 64) {
        const float4* vp = (const float4*)(vs + (size_t)(V0 + voff) * 32 + kg * 8);
        float4 qa = vp[0];
        float4 qb = vp[1];
#pragma unroll
        for (int r = 0; r < RPB; ++r) {
            float pd = fa[r].x * qa.x + fa[r].y * qa.y + fa[r].z * qa.z + fa[r].w * qa.w
                     + fb[r].x * qb.x + fb[r].y * qb.y + fb[r].z * qb.z + fb[r].w * qb.w;
            // complete the 32-wide dot across the 4 kg lanes (quad-perm DPP)
            pd += __shfl_xor(pd, 1, 64);
            pd += __shfl_xor(pd, 2, 64);
            float w = __expf(pd * invt[r]);
            lsum[r] += w;
            aa[r].x += w * qa.x; aa[r].y += w * qa.y; aa[r].z += w * qa.z; aa[r].w += w * qa.w;
            ab[r].x += w * qb.x; ab[r].y += w * qb.y; ab[r].z += w * qb.z; ab[r].w += w * qb.w;
        }
    }

    // Reduce over vl (lanes differing in bits 2..5): masks 4,8,16,32.
#pragma unroll
    for (int r = 0; r < RPB; ++r) {
        float a[8] = {aa[r].x, aa[r].y, aa[r].z, aa[r].w,
                      ab[r].x, ab[r].y, ab[r].z, ab[r].w};
#pragma unroll
        for (int j = 0; j < 8; ++j) {
            float x = a[j];
            x += __shfl_xor(x, 4, 64);
            x += __shfl_xor(x, 8, 64);
            x += __shfl_xor(x, 16, 64);
            x += __shfl_xor(x, 32, 64);
            a[j] = x;
        }
        float lv = lsum[r];
        lv += __shfl_xor(lv, 4, 64);
        lv += __shfl_xor(lv, 8, 64);
        lv += __shfl_xor(lv, 16, 64);
        lv += __shfl_xor(lv, 32, 64);
        if (vl == 0) {
#pragma unroll
            for (int j = 0; j < 8; ++j) red[wave][r * 33 + kg * 8 + j] = a[j];
            if (kg == 0) red[wave][r * 33 + 32] = lv;
        }
    }
    __syncthreads();

    if (tid < RPB * 33) {
        float s = red[0][tid] + red[1][tid] + red[2][tid] + red[3][tid];
        part[(size_t)b * (RPB * 33) + tid] = s;
    }
}

// ---------------- Kernel D: combine V-slice partials ----------------
__global__ void combine_kernel(const float* __restrict__ part, float* __restrict__ out) {
    int t = blockIdx.x * 256 + threadIdx.x;      // t = frow*32 + h
    if (t >= MROWS * NHD) return;
    int frow = t >> 5, h = t & 31;
    int rg = frow >> 2, i = frow & 3;
    float a = 0.f, l = 0.f;
#pragma unroll
    for (int s = 0; s < VSLICES; ++s) {
        const float* p = part + (size_t)(rg * VSLICES + s) * (RPB * 33) + i * 33;
        a += p[h];
        l += p[32];
    }
    out[t] = a / l;
}

extern "C" void kernel_launch(void* const* d_in, const int* in_sizes, int n_in,
                              void* d_out, int out_size, void* d_ws, size_t ws_size,
                              hipStream_t stream) {
    const float* x     = (const float*)d_in[0];   // (2,64,1024)
    const float* W     = (const float*)d_in[1];   // (32,32)
    const float* bias  = (const float*)d_in[2];   // (32,)
    const float* temps = (const float*)d_in[3];   // (32,)
    const float* emb   = (const float*)d_in[4];   // (32000,1024)
    float* out = (float*)d_out;                   // (2,64,1024) fp32

    float* ws   = (float*)d_ws;
    float* vs   = ws + WS_VS_OFF;
    float* F    = ws + WS_F_OFF;
    float* part = ws + WS_PART_OFF;

    vsum_kernel<<<(NV * NHD + 255) / 256, 256, 0, stream>>>(emb, vs);
    ffn_kernel<<<(MROWS * NHD + 255) / 256, 256, 0, stream>>>(x, W, bias, F);
    fused_kernel<<<(MROWS / RPB) * VSLICES, 256, 0, stream>>>(vs, F, temps, part);
    combine_kernel<<<(MROWS * NHD + 255) / 256, 256, 0, stream>>>(part, out);
}

// Round 3
// 80.989 us; speedup vs baseline: 40.9450x; 4.8464x over previous
//
#include <hip/hip_runtime.h>
#include <hip/hip_bf16.h>

// B=2,T=64,V=32000,NH=32,HD=32. BT=128, M = BT*NH = 4096 rows, D=32.
// Flash-attn formulation: Q=F (4096x32), K=V=vs (32000x32),
// S=Q.vs^T, P=exp(S/T), out = P.vs / rowsum(P).
#define NV      32000
#define MROWS   4096
#define NQT     128            // MROWS/32 q-tiles
#define NSLICE  10
#define CHUNKS_PER_SLICE 100   // of 1000 total 32-v chunks
#define CHUNKS_PER_WAVE  25
#define PART_STRIDE 1088       // 32x32 acc + 2x32 lsum halves

typedef __attribute__((ext_vector_type(8))) short short8;
typedef __attribute__((ext_vector_type(16))) float f32x16;

// ws layout (bytes):
//   vsb  [NV][32]  bf16 : 0          (2,048,000)
//   vstb [32][NV]  bf16 : 2,048,000  (2,048,000)
//   Fb   [M][32]   bf16 : 4,096,000  (262,144)
//   part [1280][1088] f32 : 4,358,144 (5,570,560)   total ~9.93 MB
#define OFF_VSB  0
#define OFF_VSTB 2048000
#define OFF_FB   4096000
#define OFF_PART 4358144

static __device__ __forceinline__ unsigned pkbf(float lo, float hi) {
    union { __hip_bfloat162 h; unsigned u; } cv;
    cv.h.x = __float2bfloat16(lo);
    cv.h.y = __float2bfloat16(hi);
    return cv.u;
}

// ---------------- prep: vocab channel sums -> bf16 vs + vs^T ----------------
__global__ void prep_vs(const float* __restrict__ emb,
                        unsigned short* __restrict__ vsb,
                        unsigned short* __restrict__ vstb) {
    int t = blockIdx.x * 256 + threadIdx.x;      // t = v*32 + h
    if (t >= NV * 32) return;
    int v = t >> 5, h = t & 31;
    const float4* p = (const float4*)(emb + (size_t)v * 1024 + h * 32);
    float s = 0.f;
#pragma unroll
    for (int i = 0; i < 8; ++i) {
        float4 a = p[i];
        s += a.x + a.y + a.z + a.w;
    }
    __hip_bfloat16 bv = __float2bfloat16(s);
    unsigned short us = *reinterpret_cast<unsigned short*>(&bv);
    vsb[t] = us;
    vstb[(size_t)h * NV + v] = us;
}

// ---------------- prep: per-head FFN -> bf16 F ----------------
__global__ void prep_f(const float* __restrict__ x, const float* __restrict__ W,
                       const float* __restrict__ b, unsigned short* __restrict__ Fb) {
    int t = blockIdx.x * 256 + threadIdx.x;      // t = frow*32 + d
    if (t >= MROWS * 32) return;
    int frow = t >> 5, d = t & 31;
    const float4* xp = (const float4*)(x + (size_t)frow * 32);
    const float4* wp = (const float4*)(W + (size_t)d * 32);
    float s = b[d];
#pragma unroll
    for (int i = 0; i < 8; ++i) {
        float4 xv = xp[i];
        float4 wv = wp[i];
        s += xv.x * wv.x + xv.y * wv.y + xv.z * wv.z + xv.w * wv.w;
    }
    __hip_bfloat16 bv = __float2bfloat16(s);
    Fb[t] = *reinterpret_cast<unsigned short*>(&bv);
}

// ---------------- fused MFMA flash kernel ----------------
// block b = s*128 + qt. 4 waves share q-tile qt, each takes 25 chunks of slice s.
// Swapped QK^T: D[v][q] -> lane(hi,c): q=c, v=crow(r,hi)=(r&3)+8*(r>>2)+4*hi.
// permlane32_swap builds PV A-frags: lane needs P[q=c][16ks+8hi+j].
__global__ __launch_bounds__(256, 4)
void fused_mfma(const unsigned short* __restrict__ vsb,
                const unsigned short* __restrict__ vstb,
                const unsigned short* __restrict__ Fb,
                const float* __restrict__ temps,
                float* __restrict__ part) {
    const int b = blockIdx.x;
    const int s = b >> 7;
    const int qt = b & 127;
    const int tid = threadIdx.x;
    const int wave = tid >> 6, lane = tid & 63;
    const int hi = lane >> 5, c = lane & 31;

    const int qrow = qt * 32 + c;
    // Q as B-operand (B[k=d][n=q] = F[q][d]): lane reads F[qrow][8hi..8hi+8)
    short8 qf0 = *(const short8*)(Fb + (size_t)qrow * 32 + 8 * hi);
    short8 qf1 = *(const short8*)(Fb + (size_t)qrow * 32 + 16 + 8 * hi);
    const float invt = 1.0f / fmaxf(temps[c], 0.1f);

    f32x16 oacc;
#pragma unroll
    for (int r = 0; r < 16; ++r) oacc[r] = 0.f;
    float lsum = 0.f;

    const int ch0 = s * CHUNKS_PER_SLICE + wave * CHUNKS_PER_WAVE;
    for (int ch = ch0; ch < ch0 + CHUNKS_PER_WAVE; ++ch) {
        const int vbase = ch * 32;
        // QK^T A-frags: vs rows, A[v=c][d=8hi+j] and d=16+8hi+j
        const unsigned short* vrow = vsb + (size_t)(vbase + c) * 32 + 8 * hi;
        short8 va0 = *(const short8*)(vrow);
        short8 va1 = *(const short8*)(vrow + 16);
        // PV B-frags: vst rows, B[kv=8hi+j][n=c] = vst[c][vbase+16ks+8hi+j]
        const unsigned short* vtrow = vstb + (size_t)c * NV + vbase + 8 * hi;
        short8 vb0 = *(const short8*)(vtrow);
        short8 vb1 = *(const short8*)(vtrow + 16);

        f32x16 sa;
#pragma unroll
        for (int r = 0; r < 16; ++r) sa[r] = 0.f;
        sa = __builtin_amdgcn_mfma_f32_32x32x16_bf16(va0, qf0, sa, 0, 0, 0);
        sa = __builtin_amdgcn_mfma_f32_32x32x16_bf16(va1, qf1, sa, 0, 0, 0);

        // softmax weights (no-max: |logit| <= ~5 in fp32, safe)
        float w[16];
#pragma unroll
        for (int r = 0; r < 16; ++r) {
            float e = __expf(sa[r] * invt);
            w[r] = e;
            lsum += e;
        }
        // pack pairs: W[p] holds v = 8*(p>>1) + 4hi + 2*(p&1) + {0,1}
        unsigned u0 = pkbf(w[0], w[1]),   u1 = pkbf(w[2], w[3]);
        unsigned u2 = pkbf(w[4], w[5]),   u3 = pkbf(w[6], w[7]);
        unsigned u4 = pkbf(w[8], w[9]),   u5 = pkbf(w[10], w[11]);
        unsigned u6 = pkbf(w[12], w[13]), u7 = pkbf(w[14], w[15]);
        // swap hi-half of dst with lo-half of src:
        // (u0,u2)->(A0_ks0, A2_ks0), (u1,u3)->(A1_ks0, A3_ks0)
        // (u4,u6)->(A0_ks1, A2_ks1), (u5,u7)->(A1_ks1, A3_ks1)
        asm volatile("v_permlane32_swap_b32 %0, %1" : "+v"(u0), "+v"(u2));
        asm volatile("v_permlane32_swap_b32 %0, %1" : "+v"(u1), "+v"(u3));
        asm volatile("v_permlane32_swap_b32 %0, %1" : "+v"(u4), "+v"(u6));
        asm volatile("v_permlane32_swap_b32 %0, %1" : "+v"(u5), "+v"(u7));

        union { unsigned u[4]; short8 v8; } pa0, pa1;
        pa0.u[0] = u0; pa0.u[1] = u1; pa0.u[2] = u2; pa0.u[3] = u3;
        pa1.u[0] = u4; pa1.u[1] = u5; pa1.u[2] = u6; pa1.u[3] = u7;

        oacc = __builtin_amdgcn_mfma_f32_32x32x16_bf16(pa0.v8, vb0, oacc, 0, 0, 0);
        oacc = __builtin_amdgcn_mfma_f32_32x32x16_bf16(pa1.v8, vb1, oacc, 0, 0, 0);
    }

    // cross-wave reduce in LDS, then write block partial
    __shared__ float red[4][64 * 17];
    float* rw = &red[wave][lane * 17];
#pragma unroll
    for (int r = 0; r < 16; ++r) rw[r] = oacc[r];
    rw[16] = lsum;
    __syncthreads();

    const size_t pbase = (size_t)b * PART_STRIDE;
    for (int idx = tid; idx < 64 * 17; idx += 256) {
        float sum = red[0][idx] + red[1][idx] + red[2][idx] + red[3][idx];
        int ln = idx / 17, k = idx - ln * 17;
        int lhi = ln >> 5, lc = ln & 31;
        int off;
        if (k < 16) off = (((k & 3) + 8 * (k >> 2) + 4 * lhi) << 5) + lc;  // q*32 + j
        else        off = 1024 + ln;                                      // lsum half
        part[pbase + off] = sum;
    }
}

// ---------------- combine slice partials ----------------
__global__ void combine_kernel(const float* __restrict__ part, float* __restrict__ out) {
    int t = blockIdx.x * 256 + threadIdx.x;      // t = qrow*32 + j
    if (t >= MROWS * 32) return;
    int qrow = t >> 5, j = t & 31;
    int qt = qrow >> 5, qi = qrow & 31;
    float a = 0.f, l = 0.f;
#pragma unroll
    for (int s = 0; s < NSLICE; ++s) {
        const float* p = part + (size_t)(s * NQT + qt) * PART_STRIDE;
        a += p[(qi << 5) + j];
        l += p[1024 + qi] + p[1024 + 32 + qi];
    }
    out[t] = a / l;
}

extern "C" void kernel_launch(void* const* d_in, const int* in_sizes, int n_in,
                              void* d_out, int out_size, void* d_ws, size_t ws_size,
                              hipStream_t stream) {
    const float* x     = (const float*)d_in[0];
    const float* W     = (const float*)d_in[1];
    const float* bias  = (const float*)d_in[2];
    const float* temps = (const float*)d_in[3];
    const float* emb   = (const float*)d_in[4];
    float* out = (float*)d_out;

    char* ws = (char*)d_ws;
    unsigned short* vsb  = (unsigned short*)(ws + OFF_VSB);
    unsigned short* vstb = (unsigned short*)(ws + OFF_VSTB);
    unsigned short* Fb   = (unsigned short*)(ws + OFF_FB);
    float*          part = (float*)(ws + OFF_PART);

    prep_vs<<<(NV * 32 + 255) / 256, 256, 0, stream>>>(emb, vsb, vstb);
    prep_f<<<(MROWS * 32 + 255) / 256, 256, 0, stream>>>(x, W, bias, Fb);
    fused_mfma<<<NSLICE * NQT, 256, 0, stream>>>(vsb, vstb, Fb, temps, part);
    combine_kernel<<<(MROWS * 32 + 255) / 256, 256, 0, stream>>>(part, out);
}

// Round 4
// 77.209 us; speedup vs baseline: 42.9495x; 1.0490x over previous
//
#include <hip/hip_runtime.h>
#include <hip/hip_bf16.h>

// B=2,T=64,V=32000,NH=32,HD=32. BT=128, M=4096 rows, D=32.
// Flash-attn formulation: Q=F (4096x32, pre-scaled by invt*log2e),
// K=V=vs (32000x32). S=Q.vs^T, P=exp2(S), out = P.vs / rowsum(P).
#define NV      32000
#define MROWS   4096
#define NQT     128            // MROWS/32 q-tiles
#define NSLICE  8
#define CHUNKS_PER_SLICE 125   // of 1000 total 32-v chunks
#define PART_STRIDE 1056       // 32x32 acc + 32 lsum

typedef __attribute__((ext_vector_type(8))) short short8;
typedef __attribute__((ext_vector_type(16))) float f32x16;

// ws layout (bytes):
//   vsb  [NV][32]  bf16 : 0          (2,048,000)
//   vstb [32][NV]  bf16 : 2,048,000  (2,048,000)
//   Fb   [M][32]   bf16 : 4,096,000  (262,144)
//   part [1024][1056] f32 : 4,358,144 (4,325,376)  total ~8.7 MB
#define OFF_VSB  0
#define OFF_VSTB 2048000
#define OFF_FB   4096000
#define OFF_PART 4358144

#define NVS_BLOCKS 4000        // NV*32/256
#define NF_BLOCKS  512         // MROWS*32/256

static __device__ __forceinline__ unsigned pkbf(float lo, float hi) {
    union { __hip_bfloat162 h; unsigned u; } cv;
    cv.h.x = __float2bfloat16(lo);
    cv.h.y = __float2bfloat16(hi);
    return cv.u;
}

// ---------------- prep: vs sums (bf16 + transpose) AND pre-scaled F ----------------
__global__ void prep_kernel(const float* __restrict__ emb,
                            const float* __restrict__ x, const float* __restrict__ W,
                            const float* __restrict__ bias, const float* __restrict__ temps,
                            unsigned short* __restrict__ vsb,
                            unsigned short* __restrict__ vstb,
                            unsigned short* __restrict__ Fb) {
    const int blk = blockIdx.x;
    if (blk < NVS_BLOCKS) {
        int t = blk * 256 + threadIdx.x;          // t = v*32 + h
        int v = t >> 5, h = t & 31;
        const float4* p = (const float4*)(emb + (size_t)v * 1024 + h * 32);
        float s = 0.f;
#pragma unroll
        for (int i = 0; i < 8; ++i) {
            float4 a = p[i];
            s += a.x + a.y + a.z + a.w;
        }
        __hip_bfloat16 bv = __float2bfloat16(s);
        unsigned short us = *reinterpret_cast<unsigned short*>(&bv);
        vsb[t] = us;
        vstb[(size_t)h * NV + v] = us;
    } else {
        int t = (blk - NVS_BLOCKS) * 256 + threadIdx.x;   // t = frow*32 + d
        int frow = t >> 5, d = t & 31;
        const float4* xp = (const float4*)(x + (size_t)frow * 32);
        const float4* wp = (const float4*)(W + (size_t)d * 32);
        float s = bias[d];
#pragma unroll
        for (int i = 0; i < 8; ++i) {
            float4 xv = xp[i];
            float4 wv = wp[i];
            s += xv.x * wv.x + xv.y * wv.y + xv.z * wv.z + xv.w * wv.w;
        }
        // fold 1/temp and log2(e) into F so inner loop is bare exp2
        float sc = 1.44269504088896f / fmaxf(temps[frow & 31], 0.1f);
        __hip_bfloat16 bv = __float2bfloat16(s * sc);
        Fb[t] = *reinterpret_cast<unsigned short*>(&bv);
    }
}

// ---------------- fused MFMA flash kernel ----------------
// b = qt*8 + s (s = b&7 -> XCD-local 512KB slice). 4 waves share q-tile qt,
// interleaved chunks ch = s*125 + wave, += 4.
// Swapped QK^T: D[v][q] -> lane(hi,c): q=c, v=(r&3)+8*(r>>2)+4*hi.
// permlane32_swap builds PV A-frags; lsum via mfma(P, ones).
__global__ __launch_bounds__(256, 4)
void fused_mfma(const unsigned short* __restrict__ vsb,
                const unsigned short* __restrict__ vstb,
                const unsigned short* __restrict__ Fb,
                float* __restrict__ part) {
    const int b = blockIdx.x;
    const int s = b & 7;
    const int qt = b >> 3;
    const int tid = threadIdx.x;
    const int wave = tid >> 6, lane = tid & 63;
    const int hi = lane >> 5, c = lane & 31;

    const int qrow = qt * 32 + c;
    short8 qf0 = *(const short8*)(Fb + (size_t)qrow * 32 + 8 * hi);
    short8 qf1 = *(const short8*)(Fb + (size_t)qrow * 32 + 16 + 8 * hi);

    union { unsigned u[4]; short8 v8; } onesb;
    onesb.u[0] = 0x3F803F80u; onesb.u[1] = 0x3F803F80u;
    onesb.u[2] = 0x3F803F80u; onesb.u[3] = 0x3F803F80u;

    f32x16 oacc, lacc;
#pragma unroll
    for (int r = 0; r < 16; ++r) { oacc[r] = 0.f; lacc[r] = 0.f; }

    for (int ch = s * CHUNKS_PER_SLICE + wave; ch < (s + 1) * CHUNKS_PER_SLICE; ch += 4) {
        const int vbase = ch * 32;
        const unsigned short* vrow = vsb + (size_t)(vbase + c) * 32 + 8 * hi;
        short8 va0 = *(const short8*)(vrow);
        short8 va1 = *(const short8*)(vrow + 16);
        const unsigned short* vtrow = vstb + (size_t)c * NV + vbase + 8 * hi;
        short8 vb0 = *(const short8*)(vtrow);
        short8 vb1 = *(const short8*)(vtrow + 16);

        f32x16 sa;
#pragma unroll
        for (int r = 0; r < 16; ++r) sa[r] = 0.f;
        sa = __builtin_amdgcn_mfma_f32_32x32x16_bf16(va0, qf0, sa, 0, 0, 0);
        sa = __builtin_amdgcn_mfma_f32_32x32x16_bf16(va1, qf1, sa, 0, 0, 0);

        // softmax weights, no max-subtraction (|S*log2e/T| small, fp32-safe)
        float w[16];
#pragma unroll
        for (int r = 0; r < 16; ++r) w[r] = __builtin_amdgcn_exp2f(sa[r]);

        unsigned u0 = pkbf(w[0], w[1]),   u1 = pkbf(w[2], w[3]);
        unsigned u2 = pkbf(w[4], w[5]),   u3 = pkbf(w[6], w[7]);
        unsigned u4 = pkbf(w[8], w[9]),   u5 = pkbf(w[10], w[11]);
        unsigned u6 = pkbf(w[12], w[13]), u7 = pkbf(w[14], w[15]);
        asm volatile("v_permlane32_swap_b32 %0, %1" : "+v"(u0), "+v"(u2));
        asm volatile("v_permlane32_swap_b32 %0, %1" : "+v"(u1), "+v"(u3));
        asm volatile("v_permlane32_swap_b32 %0, %1" : "+v"(u4), "+v"(u6));
        asm volatile("v_permlane32_swap_b32 %0, %1" : "+v"(u5), "+v"(u7));

        union { unsigned u[4]; short8 v8; } pa0, pa1;
        pa0.u[0] = u0; pa0.u[1] = u1; pa0.u[2] = u2; pa0.u[3] = u3;
        pa1.u[0] = u4; pa1.u[1] = u5; pa1.u[2] = u6; pa1.u[3] = u7;

        oacc = __builtin_amdgcn_mfma_f32_32x32x16_bf16(pa0.v8, vb0, oacc, 0, 0, 0);
        oacc = __builtin_amdgcn_mfma_f32_32x32x16_bf16(pa1.v8, vb1, oacc, 0, 0, 0);
        // rowsum(P) on the matrix pipe: lacc[r] = lsum[q_r] (all columns equal)
        lacc = __builtin_amdgcn_mfma_f32_32x32x16_bf16(pa0.v8, onesb.v8, lacc, 0, 0, 0);
        lacc = __builtin_amdgcn_mfma_f32_32x32x16_bf16(pa1.v8, onesb.v8, lacc, 0, 0, 0);
    }

    // cross-wave reduce in LDS, then write block partial
    __shared__ float red[4][64 * 17];   // stride 17 floats: bank-conflict-free
    __shared__ float lred[4][32];
    float* rw = &red[wave][lane * 17];
#pragma unroll
    for (int r = 0; r < 16; ++r) rw[r] = oacc[r];
    if (c == 0) {
#pragma unroll
        for (int r = 0; r < 16; ++r)
            lred[wave][(r & 3) + 8 * (r >> 2) + 4 * hi] = lacc[r];
    }
    __syncthreads();

    const size_t pbase = (size_t)b * PART_STRIDE;
    for (int idx = tid; idx < 1024; idx += 256) {
        int ln = idx >> 4, r = idx & 15;
        float sum = red[0][ln * 17 + r] + red[1][ln * 17 + r]
                  + red[2][ln * 17 + r] + red[3][ln * 17 + r];
        int lhi = ln >> 5, lc = ln & 31;
        int q = (r & 3) + 8 * (r >> 2) + 4 * lhi;
        part[pbase + (q << 5) + lc] = sum;
    }
    if (tid < 32)
        part[pbase + 1024 + tid] = lred[0][tid] + lred[1][tid] + lred[2][tid] + lred[3][tid];
}

// ---------------- combine slice partials ----------------
__global__ void combine_kernel(const float* __restrict__ part, float* __restrict__ out) {
    int t = blockIdx.x * 256 + threadIdx.x;      // t = qrow*32 + j
    if (t >= MROWS * 32) return;
    int qrow = t >> 5, j = t & 31;
    int qt = qrow >> 5, qi = qrow & 31;
    float a = 0.f, l = 0.f;
#pragma unroll
    for (int s = 0; s < NSLICE; ++s) {
        const float* p = part + (size_t)(qt * NSLICE + s) * PART_STRIDE;
        a += p[(qi << 5) + j];
        l += p[1024 + qi];
    }
    out[t] = a / l;
}

extern "C" void kernel_launch(void* const* d_in, const int* in_sizes, int n_in,
                              void* d_out, int out_size, void* d_ws, size_t ws_size,
                              hipStream_t stream) {
    const float* x     = (const float*)d_in[0];
    const float* W     = (const float*)d_in[1];
    const float* bias  = (const float*)d_in[2];
    const float* temps = (const float*)d_in[3];
    const float* emb   = (const float*)d_in[4];
    float* out = (float*)d_out;

    char* ws = (char*)d_ws;
    unsigned short* vsb  = (unsigned short*)(ws + OFF_VSB);
    unsigned short* vstb = (unsigned short*)(ws + OFF_VSTB);
    unsigned short* Fb   = (unsigned short*)(ws + OFF_FB);
    float*          part = (float*)(ws + OFF_PART);

    prep_kernel<<<NVS_BLOCKS + NF_BLOCKS, 256, 0, stream>>>(emb, x, W, bias, temps,
                                                            vsb, vstb, Fb);
    fused_mfma<<<NSLICE * NQT, 256, 0, stream>>>(vsb, vstb, Fb, part);
    combine_kernel<<<(MROWS * 32 + 255) / 256, 256, 0, stream>>>(part, out);
}

// Round 5
// 60.754 us; speedup vs baseline: 54.5819x; 1.2708x over previous
//
#include <hip/hip_runtime.h>
#include <hip/hip_bf16.h>

// B=2,T=64,V=32000,NH=32,HD=32. BT=128, M=4096 rows, D=32.
// Flash-attn formulation: Q=F (4096x32, pre-scaled by invt*log2e),
// K=V=vs (32000x32). S=Q.vs^T, P=exp2(S), out = P.vs / rowsum(P).
#define NV      32000
#define MROWS   4096
#define NSLICE  8
#define CHUNKS_PER_SLICE 125   // of 1000 total 32-v chunks
#define PART_STRIDE 1056       // 32x32 acc + 32 lsum

typedef __attribute__((ext_vector_type(8))) short short8;
typedef __attribute__((ext_vector_type(16))) float f32x16;

// ws layout (bytes):
//   vsb  [NV][32]  bf16 : 0          (2,048,000)
//   vstb [32][NV]  bf16 : 2,048,000  (2,048,000)
//   Fb   [M][32]   bf16 : 4,096,000  (262,144)
//   part [1024][1056] f32 : 4,358,144 (4,325,376)  total ~8.7 MB
#define OFF_VSB  0
#define OFF_VSTB 2048000
#define OFF_FB   4096000
#define OFF_PART 4358144

#define NVS_BLOCKS 1000        // 32 v-rows per block
#define NF_BLOCKS  512         // MROWS*32/256

static __device__ __forceinline__ unsigned pkbf(float lo, float hi) {
    union { __hip_bfloat162 h; unsigned u; } cv;
    cv.h.x = __float2bfloat16(lo);
    cv.h.y = __float2bfloat16(hi);
    return cv.u;
}

// ---------------- prep: vs sums (bf16 + transpose, coalesced) AND scaled F ----------------
__global__ __launch_bounds__(256)
void prep_kernel(const float* __restrict__ emb,
                 const float* __restrict__ x, const float* __restrict__ W,
                 const float* __restrict__ bias, const float* __restrict__ temps,
                 unsigned short* __restrict__ vsb,
                 unsigned short* __restrict__ vstb,
                 unsigned short* __restrict__ Fb) {
    const int blk = blockIdx.x;
    const int tid = threadIdx.x;
    if (blk < NVS_BLOCKS) {
        const int vbase = blk * 32;
        const int wave = tid >> 6, lane = tid & 63;
        __shared__ float lds[32][33];
        // wave handles v-rows vl = wave, wave+4, ... (8 rows); 4KB coalesced read per row
        for (int vl = wave; vl < 32; vl += 4) {
            const float4* p = (const float4*)(emb + (size_t)(vbase + vl) * 1024) + lane;
            float4 a0 = p[0], a1 = p[64], a2 = p[128], a3 = p[192];
            float s0 = a0.x + a0.y + a0.z + a0.w;
            float s1 = a1.x + a1.y + a1.z + a1.w;
            float s2 = a2.x + a2.y + a2.z + a2.w;
            float s3 = a3.x + a3.y + a3.z + a3.w;
            // reduce over lanes within 8-lane groups (same h = lane>>3)
            s0 += __shfl_xor(s0, 1, 64); s0 += __shfl_xor(s0, 2, 64); s0 += __shfl_xor(s0, 4, 64);
            s1 += __shfl_xor(s1, 1, 64); s1 += __shfl_xor(s1, 2, 64); s1 += __shfl_xor(s1, 4, 64);
            s2 += __shfl_xor(s2, 1, 64); s2 += __shfl_xor(s2, 2, 64); s2 += __shfl_xor(s2, 4, 64);
            s3 += __shfl_xor(s3, 1, 64); s3 += __shfl_xor(s3, 2, 64); s3 += __shfl_xor(s3, 4, 64);
            if ((lane & 7) == 0) {
                int hb = lane >> 3;
                lds[vl][hb]      = s0;
                lds[vl][hb + 8]  = s1;
                lds[vl][hb + 16] = s2;
                lds[vl][hb + 24] = s3;
            }
        }
        __syncthreads();
        // vsb: thread writes 4 shorts (8B): e = tid*4 -> v=tid>>3, h=(tid&7)*4
        {
            int v = tid >> 3, h = (tid & 7) * 4;
            union { unsigned u[2]; ushort2 s2[2]; } o;
            o.u[0] = pkbf(lds[v][h],     lds[v][h + 1]);
            o.u[1] = pkbf(lds[v][h + 2], lds[v][h + 3]);
            *(uint2*)(vsb + (size_t)(vbase + v) * 32 + h) = *(uint2*)o.u;
        }
        // vstb: thread writes 4 shorts (8B) of row h: h = tid>>3, vi=(tid&7)*4
        {
            int h = tid >> 3, vi = (tid & 7) * 4;
            union { unsigned u[2]; } o;
            o.u[0] = pkbf(lds[vi][h],     lds[vi + 1][h]);
            o.u[1] = pkbf(lds[vi + 2][h], lds[vi + 3][h]);
            *(uint2*)(vstb + (size_t)h * NV + vbase + vi) = *(uint2*)o.u;
        }
    } else {
        int t = (blk - NVS_BLOCKS) * 256 + tid;   // t = frow*32 + d
        int frow = t >> 5, d = t & 31;
        const float4* xp = (const float4*)(x + (size_t)frow * 32);
        const float4* wp = (const float4*)(W + (size_t)d * 32);
        float s = bias[d];
#pragma unroll
        for (int i = 0; i < 8; ++i) {
            float4 xv = xp[i];
            float4 wv = wp[i];
            s += xv.x * wv.x + xv.y * wv.y + xv.z * wv.z + xv.w * wv.w;
        }
        // fold 1/temp and log2(e) into F so inner loop is bare exp2
        float sc = 1.44269504088896f / fmaxf(temps[frow & 31], 0.1f);
        __hip_bfloat16 bv = __float2bfloat16(s * sc);
        Fb[t] = *reinterpret_cast<unsigned short*>(&bv);
    }
}

// ---------------- fused MFMA flash kernel: 2 q-tiles per block ----------------
// b = qp*8 + s. Block owns q-rows [qp*64, qp*64+64) as tiles qt0=2qp, qt1=2qp+1,
// sharing every vs/vst chunk read. 4 waves interleave chunks of slice s.
// Swapped QK^T: D[v][q] -> lane(hi,c): q=c, v=(r&3)+8*(r>>2)+4*hi.
// permlane32_swap builds PV A-frags; lsum via mfma(P, ones).
__global__ __launch_bounds__(256, 2)
void fused_mfma(const unsigned short* __restrict__ vsb,
                const unsigned short* __restrict__ vstb,
                const unsigned short* __restrict__ Fb,
                float* __restrict__ part) {
    const int b = blockIdx.x;
    const int s = b & 7;
    const int qp = b >> 3;
    const int tid = threadIdx.x;
    const int wave = tid >> 6, lane = tid & 63;
    const int hi = lane >> 5, c = lane & 31;

    const int qrow0 = qp * 64 + c;
    short8 q0a = *(const short8*)(Fb + (size_t)qrow0 * 32 + 8 * hi);
    short8 q0b = *(const short8*)(Fb + (size_t)qrow0 * 32 + 16 + 8 * hi);
    short8 q1a = *(const short8*)(Fb + (size_t)(qrow0 + 32) * 32 + 8 * hi);
    short8 q1b = *(const short8*)(Fb + (size_t)(qrow0 + 32) * 32 + 16 + 8 * hi);

    union { unsigned u[4]; short8 v8; } onesb;
    onesb.u[0] = 0x3F803F80u; onesb.u[1] = 0x3F803F80u;
    onesb.u[2] = 0x3F803F80u; onesb.u[3] = 0x3F803F80u;

    f32x16 oacc0, oacc1, lacc0, lacc1;
#pragma unroll
    for (int r = 0; r < 16; ++r) { oacc0[r] = 0.f; oacc1[r] = 0.f; lacc0[r] = 0.f; lacc1[r] = 0.f; }

    for (int ch = s * CHUNKS_PER_SLICE + wave; ch < (s + 1) * CHUNKS_PER_SLICE; ch += 4) {
        const int vbase = ch * 32;
        const unsigned short* vrow = vsb + (size_t)(vbase + c) * 32 + 8 * hi;
        short8 va0 = *(const short8*)(vrow);
        short8 va1 = *(const short8*)(vrow + 16);
        const unsigned short* vtrow = vstb + (size_t)c * NV + vbase + 8 * hi;
        short8 vb0 = *(const short8*)(vtrow);
        short8 vb1 = *(const short8*)(vtrow + 16);

#pragma unroll
        for (int t = 0; t < 2; ++t) {
            f32x16 sa;
#pragma unroll
            for (int r = 0; r < 16; ++r) sa[r] = 0.f;
            sa = __builtin_amdgcn_mfma_f32_32x32x16_bf16(va0, t ? q1a : q0a, sa, 0, 0, 0);
            sa = __builtin_amdgcn_mfma_f32_32x32x16_bf16(va1, t ? q1b : q0b, sa, 0, 0, 0);

            float w[16];
#pragma unroll
            for (int r = 0; r < 16; ++r) w[r] = __builtin_amdgcn_exp2f(sa[r]);

            unsigned u0 = pkbf(w[0], w[1]),   u1 = pkbf(w[2], w[3]);
            unsigned u2 = pkbf(w[4], w[5]),   u3 = pkbf(w[6], w[7]);
            unsigned u4 = pkbf(w[8], w[9]),   u5 = pkbf(w[10], w[11]);
            unsigned u6 = pkbf(w[12], w[13]), u7 = pkbf(w[14], w[15]);
            asm volatile("v_permlane32_swap_b32 %0, %1" : "+v"(u0), "+v"(u2));
            asm volatile("v_permlane32_swap_b32 %0, %1" : "+v"(u1), "+v"(u3));
            asm volatile("v_permlane32_swap_b32 %0, %1" : "+v"(u4), "+v"(u6));
            asm volatile("v_permlane32_swap_b32 %0, %1" : "+v"(u5), "+v"(u7));

            union { unsigned u[4]; short8 v8; } pa0, pa1;
            pa0.u[0] = u0; pa0.u[1] = u1; pa0.u[2] = u2; pa0.u[3] = u3;
            pa1.u[0] = u4; pa1.u[1] = u5; pa1.u[2] = u6; pa1.u[3] = u7;

            if (t == 0) {
                oacc0 = __builtin_amdgcn_mfma_f32_32x32x16_bf16(pa0.v8, vb0, oacc0, 0, 0, 0);
                oacc0 = __builtin_amdgcn_mfma_f32_32x32x16_bf16(pa1.v8, vb1, oacc0, 0, 0, 0);
                lacc0 = __builtin_amdgcn_mfma_f32_32x32x16_bf16(pa0.v8, onesb.v8, lacc0, 0, 0, 0);
                lacc0 = __builtin_amdgcn_mfma_f32_32x32x16_bf16(pa1.v8, onesb.v8, lacc0, 0, 0, 0);
            } else {
                oacc1 = __builtin_amdgcn_mfma_f32_32x32x16_bf16(pa0.v8, vb0, oacc1, 0, 0, 0);
                oacc1 = __builtin_amdgcn_mfma_f32_32x32x16_bf16(pa1.v8, vb1, oacc1, 0, 0, 0);
                lacc1 = __builtin_amdgcn_mfma_f32_32x32x16_bf16(pa0.v8, onesb.v8, lacc1, 0, 0, 0);
                lacc1 = __builtin_amdgcn_mfma_f32_32x32x16_bf16(pa1.v8, onesb.v8, lacc1, 0, 0, 0);
            }
        }
    }

    // cross-wave reduce in LDS (both tiles), then write block partials
    __shared__ float red[2][4][64 * 17];   // stride 17: bank-conflict-free
    __shared__ float lred[2][4][32];
    {
        float* rw0 = &red[0][wave][lane * 17];
        float* rw1 = &red[1][wave][lane * 17];
#pragma unroll
        for (int r = 0; r < 16; ++r) { rw0[r] = oacc0[r]; rw1[r] = oacc1[r]; }
        if (c == 0) {
#pragma unroll
            for (int r = 0; r < 16; ++r) {
                int q = (r & 3) + 8 * (r >> 2) + 4 * hi;
                lred[0][wave][q] = lacc0[r];
                lred[1][wave][q] = lacc1[r];
            }
        }
    }
    __syncthreads();

#pragma unroll
    for (int t = 0; t < 2; ++t) {
        const size_t pbase = (size_t)((qp * 2 + t) * NSLICE + s) * PART_STRIDE;
        for (int idx = tid; idx < 1024; idx += 256) {
            int ln = idx >> 4, r = idx & 15;
            float sum = red[t][0][ln * 17 + r] + red[t][1][ln * 17 + r]
                      + red[t][2][ln * 17 + r] + red[t][3][ln * 17 + r];
            int lhi = ln >> 5, lc = ln & 31;
            int q = (r & 3) + 8 * (r >> 2) + 4 * lhi;
            part[pbase + (q << 5) + lc] = sum;
        }
        if (tid < 32)
            part[pbase + 1024 + tid] = lred[t][0][tid] + lred[t][1][tid]
                                     + lred[t][2][tid] + lred[t][3][tid];
    }
}

// ---------------- combine slice partials ----------------
__global__ void combine_kernel(const float* __restrict__ part, float* __restrict__ out) {
    int t = blockIdx.x * 256 + threadIdx.x;      // t = qrow*32 + j
    if (t >= MROWS * 32) return;
    int qrow = t >> 5, j = t & 31;
    int qt = qrow >> 5, qi = qrow & 31;
    float a = 0.f, l = 0.f;
#pragma unroll
    for (int s = 0; s < NSLICE; ++s) {
        const float* p = part + (size_t)(qt * NSLICE + s) * PART_STRIDE;
        a += p[(qi << 5) + j];
        l += p[1024 + qi];
    }
    out[t] = a / l;
}

extern "C" void kernel_launch(void* const* d_in, const int* in_sizes, int n_in,
                              void* d_out, int out_size, void* d_ws, size_t ws_size,
                              hipStream_t stream) {
    const float* x     = (const float*)d_in[0];
    const float* W     = (const float*)d_in[1];
    const float* bias  = (const float*)d_in[2];
    const float* temps = (const float*)d_in[3];
    const float* emb   = (const float*)d_in[4];
    float* out = (float*)d_out;

    char* ws = (char*)d_ws;
    unsigned short* vsb  = (unsigned short*)(ws + OFF_VSB);
    unsigned short* vstb = (unsigned short*)(ws + OFF_VSTB);
    unsigned short* Fb   = (unsigned short*)(ws + OFF_FB);
    float*          part = (float*)(ws + OFF_PART);

    prep_kernel<<<NVS_BLOCKS + NF_BLOCKS, 256, 0, stream>>>(emb, x, W, bias, temps,
                                                            vsb, vstb, Fb);
    fused_mfma<<<64 * NSLICE, 256, 0, stream>>>(vsb, vstb, Fb, part);
    combine_kernel<<<(MROWS * 32 + 255) / 256, 256, 0, stream>>>(part, out);
}